// Round 7
// baseline (206.377 us; speedup 1.0000x reference)
//
#include <hip/hip_runtime.h>

// PolicyNetGCN on MI355X — round 7.
// Edge build is now two-phase, scatter-free at HBM granularity:
//   phase1: coarse-bucket (row>>6) append, regions split PER XCD
//           (s_getreg HW_REG_XCC_ID) -> sequential, L2-local, coalesced.
//   phase2: one block per bucket; scatter into a 16 KB LDS image of the
//           64 row-buckets (LDS atomics), then contiguous 16 KB store.
//           Zero padding for the maskless spmm comes free (LDS zeroed).
// MFMA gemms; spmm = 2 channel-half passes, 8 edges in flight, maskless.

typedef _Float16 fp16_t;
typedef _Float16 h2 __attribute__((ext_vector_type(2)));  // 4 B
typedef _Float16 h8 __attribute__((ext_vector_type(8)));  // 16 B
typedef float    f4 __attribute__((ext_vector_type(4)));
typedef unsigned long long ull;

#define CAP  64   // slots per row; P(deg>64 | ~Poisson(16)) ~ 2e-18
#define RPB  64   // rows per coarse bucket
#define SCAP 256  // per-XCD per-bucket capacity (mean 128, sd 11 -> 11 sigma)

// phase 1: coarse partition, XCD-local append regions
__global__ __launch_bounds__(256) void build1_k(const int* __restrict__ erow,
                                                const int* __restrict__ ecol,
                                                const float* __restrict__ ew,
                                                int* __restrict__ bcnt,
                                                ull* __restrict__ bed,
                                                int E, int NB) {
    int e = blockIdx.x * 256 + threadIdx.x;
    if (e >= E) return;
    unsigned xcd;
    asm volatile("s_getreg_b32 %0, hwreg(HW_REG_XCC_ID)" : "=s"(xcd));
    xcd &= 7;
    int r = erow[e];
    unsigned q = (unsigned)(ew[e] * 32767.f + 0.5f);  // 15-bit fixed
    ull v = ((ull)(r & 63) << 32) | (q << 17) | (unsigned)ecol[e];
    int reg = (int)xcd * NB + (r >> 6);
    int slot = atomicAdd(&bcnt[reg], 1);
    if (slot < SCAP) bed[(size_t)reg * SCAP + slot] = v;
}

// phase 2: LDS-staged fine scatter, fully coalesced global writes
__global__ __launch_bounds__(256) void build2_k(const ull* __restrict__ bed,
                                                const int* __restrict__ bcnt,
                                                unsigned* __restrict__ ed,
                                                int* __restrict__ cnt, int NB) {
    __shared__ unsigned sbuf[RPB * CAP];  // 16 KB
    __shared__ int scnt[RPB];
    int b = blockIdx.x, tid = threadIdx.x;
    for (int i = tid; i < RPB * CAP; i += 256) sbuf[i] = 0;
    if (tid < RPB) scnt[tid] = 0;
    __syncthreads();
#pragma unroll
    for (int x = 0; x < 8; ++x) {
        int reg = x * NB + b;
        int n = bcnt[reg];
        n = n < SCAP ? n : SCAP;
        const ull* p = bed + (size_t)reg * SCAP;
        for (int i = tid; i < n; i += 256) {
            ull v = p[i];
            int rl = (int)(v >> 32);
            int pos = atomicAdd(&scnt[rl], 1);
            if (pos < CAP) sbuf[(rl << 6) + pos] = (unsigned)v;
        }
    }
    __syncthreads();
    for (int i = tid; i < RPB * CAP; i += 256)
        ed[(size_t)b * (RPB * CAP) + i] = sbuf[i];
    if (tid < RPB) {
        int c = scnt[tid];
        cnt[b * RPB + tid] = c < CAP ? c : CAP;
    }
}

// MFMA gemm: support[n, wave*64+p] = bias[p] + sum_k x[n,wave,k] * W[k,p]
// mfma_f32_16x16x32_f16 fragment maps (measured, m89/m91):
//   A: row=lane&15, k=8*(lane>>4)+t   B: col=lane&15, same k
//   C/D: col=lane&15, row=4*(lane>>4)+reg
template <int L1>
__global__ __launch_bounds__(256) void gemmM_k(const float* __restrict__ xf,
                                               const fp16_t* __restrict__ xh,
                                               const float* __restrict__ W,
                                               const float* __restrict__ bias,
                                               fp16_t* __restrict__ out, int N) {
    int wave = threadIdx.x >> 6;       // batch 0..3
    int lane = threadIdx.x & 63;
    int r16 = lane & 15, half = lane >> 4;

    h8 Bf[2][4];
#pragma unroll
    for (int kk = 0; kk < 2; ++kk)
#pragma unroll
        for (int j = 0; j < 4; ++j) {
            h8 v;
#pragma unroll
            for (int t = 0; t < 8; ++t)
                v[t] = (_Float16)W[(32 * kk + 8 * half + t) * 64 + 16 * j + r16];
            Bf[kk][j] = v;
        }
    float bj[4];
#pragma unroll
    for (int j = 0; j < 4; ++j) bj[j] = bias[16 * j + r16];

    int ntile = N >> 4;  // N % 16 == 0
    for (int tile = blockIdx.x; tile < ntile; tile += gridDim.x) {
        int row = tile * 16 + r16;
        h8 A0, A1;
        if (L1) {
            const float* p = xf + ((size_t)wave * N + row) * 64 + 8 * half;
            f4 u0 = *(const f4*)p;
            f4 u1 = *(const f4*)(p + 4);
            f4 u2 = *(const f4*)(p + 32);
            f4 u3 = *(const f4*)(p + 36);
#pragma unroll
            for (int t = 0; t < 4; ++t) {
                A0[t] = (_Float16)u0[t]; A0[t + 4] = (_Float16)u1[t];
                A1[t] = (_Float16)u2[t]; A1[t + 4] = (_Float16)u3[t];
            }
        } else {
            const fp16_t* p = xh + (size_t)row * 256 + wave * 64 + 8 * half;
            A0 = *(const h8*)p;
            A1 = *(const h8*)(p + 32);
        }
#pragma unroll
        for (int j = 0; j < 4; ++j) {
            f4 c = {0.f, 0.f, 0.f, 0.f};
            c = __builtin_amdgcn_mfma_f32_16x16x32_f16(A0, Bf[0][j], c, 0, 0, 0);
            c = __builtin_amdgcn_mfma_f32_16x16x32_f16(A1, Bf[1][j], c, 0, 0, 0);
#pragma unroll
            for (int r = 0; r < 4; ++r) {
                int orow = tile * 16 + 4 * half + r;
                out[(size_t)orow * 256 + wave * 64 + 16 * j + r16] =
                    (fp16_t)(c[r] + bj[j]);
            }
        }
    }
}

// One edge: decode packed (col|w15), gather 4 B (h2) of this pass's 256 B
// half-row, accumulate. Zero slots: w=0, col=0 (harmless read).
#define EDGE(pk)                                                               \
    {                                                                          \
        unsigned _p = (pk);                                                    \
        float _w = (float)(_p >> 17) * (1.f / 32767.f);                        \
        h2 _v = base[(size_t)(_p & 0x1FFFFu) * 128];                           \
        a0 += _w * (float)_v.x; a1 += _w * (float)_v.y;                        \
    }

// Wave = one output row; lane owns channel pair {2*(OFF+lane), +1}.
// 8 edges/iteration, maskless (slots zero-padded), 8 gathers in flight.
#define SPMM_CORE(OFF)                                                         \
    int rowi = blockIdx.x * 4 + (int)(threadIdx.x >> 6);                       \
    int lane = threadIdx.x & 63;                                               \
    int m = __builtin_amdgcn_readfirstlane(cnt[rowi]);                         \
    int mr = (m + 7) & ~7;                                                     \
    const unsigned* ep = ed + (size_t)rowi * CAP;                              \
    const h2* base = (const h2*)flat + (OFF) + lane;                           \
    float a0 = 0.f, a1 = 0.f;                                                  \
    for (int j = 0; j < mr; j += 8) {                                          \
        uint4 pA = *(const uint4*)(ep + j);                                    \
        uint4 pB = *(const uint4*)(ep + j + 4);                                \
        EDGE(pA.x) EDGE(pA.y) EDGE(pA.z) EDGE(pA.w)                            \
        EDGE(pB.x) EDGE(pB.y) EDGE(pB.z) EDGE(pB.w)                            \
    }

// layer-1 spmm pass: relu -> fp16 agg half
template <int PASS>
__global__ __launch_bounds__(256) void spmm1_k(const fp16_t* __restrict__ flat,
                                               const int* __restrict__ cnt,
                                               const unsigned* __restrict__ ed,
                                               fp16_t* __restrict__ agg, int N) {
    SPMM_CORE(PASS * 64)
    h2 r;
    r.x = (fp16_t)fmaxf(a0, 0.f);
    r.y = (fp16_t)fmaxf(a1, 0.f);
    ((h2*)agg)[(size_t)rowi * 128 + PASS * 64 + lane] = r;
}

// layer-2 spmm pass fused with head: pass owns batches {2*PASS, 2*PASS+1}.
// lane -> ch = 2*(PASS*64+lane); b = ch>>6; d = 2*(lane&31).
template <int PASS>
__global__ __launch_bounds__(256) void spmm2h_k(const fp16_t* __restrict__ flat,
                                                const int* __restrict__ cnt,
                                                const unsigned* __restrict__ ed,
                                                const float* __restrict__ wout,
                                                float* __restrict__ out, int N) {
    SPMM_CORE(PASS * 64)
    int b = 2 * PASS + (lane >> 5);
    float2 wo = ((const float2*)wout)[lane & 31];
    float p = fmaxf(a0, 0.f) * wo.x + fmaxf(a1, 0.f) * wo.y;
    p += __shfl_xor(p, 1); p += __shfl_xor(p, 2); p += __shfl_xor(p, 4);
    p += __shfl_xor(p, 8); p += __shfl_xor(p, 16);
    if ((lane & 31) == 0) out[(size_t)b * N + rowi] = p;
}

extern "C" void kernel_launch(void* const* d_in, const int* in_sizes, int n_in,
                              void* d_out, int out_size, void* d_ws, size_t ws_size,
                              hipStream_t stream) {
    const float* state = (const float*)d_in[0];
    const int*   erow  = (const int*)d_in[1];
    const int*   ecol  = (const int*)d_in[2];
    const float* ew    = (const float*)d_in[3];
    const float* W1    = (const float*)d_in[4];
    const float* b1    = (const float*)d_in[5];
    const float* W2    = (const float*)d_in[6];
    const float* b2    = (const float*)d_in[7];
    const float* wout  = (const float*)d_in[8];
    float* out = (float*)d_out;

    int N = in_sizes[0] / (4 * 64);  // 50000
    int E = in_sizes[1];             // 800000
    int NB = (N + RPB - 1) / RPB;    // 782 coarse buckets

    char* ws = (char*)d_ws;
    size_t off = 0;
    auto alloc = [&](size_t bytes) -> char* {
        char* p = ws + off;
        off += (bytes + 255) & ~(size_t)255;
        return p;
    };
    fp16_t*   flat = (fp16_t*)alloc((size_t)N * 256 * 2);            // 25.6 MB
    fp16_t*   agg  = (fp16_t*)alloc((size_t)N * 256 * 2);            // 25.6 MB
    int*      cnt  = (int*)alloc((size_t)NB * RPB * 4);              // 200 KB
    unsigned* ed   = (unsigned*)alloc((size_t)NB * RPB * CAP * 4);   // 12.8 MB
    int*      bcnt = (int*)alloc((size_t)8 * NB * 4);                // 25 KB
    ull*      bed  = (ull*)alloc((size_t)8 * NB * SCAP * 8);         // 12.8 MB
    if (off > ws_size) return;

    // --- two-phase edge build ---
    hipMemsetAsync(bcnt, 0, (size_t)8 * NB * 4, stream);
    build1_k<<<(E + 255) / 256, 256, 0, stream>>>(erow, ecol, ew, bcnt, bed, E, NB);
    build2_k<<<NB, 256, 0, stream>>>(bed, bcnt, ed, cnt, NB);

    int sg = (N + 3) / 4;  // 12500 blocks, 4 rows each
    // --- layer 1 ---
    gemmM_k<1><<<1024, 256, 0, stream>>>(state, (const fp16_t*)nullptr, W1, b1, flat, N);
    spmm1_k<0><<<sg, 256, 0, stream>>>(flat, cnt, ed, agg, N);
    spmm1_k<1><<<sg, 256, 0, stream>>>(flat, cnt, ed, agg, N);
    // --- layer 2 + head ---
    gemmM_k<0><<<1024, 256, 0, stream>>>(nullptr, agg, W2, b2, flat, N);
    spmm2h_k<0><<<sg, 256, 0, stream>>>(flat, cnt, ed, wout, out, N);
    spmm2h_k<1><<<sg, 256, 0, stream>>>(flat, cnt, ed, wout, out, N);
}

// Round 8
// 177.090 us; speedup vs baseline: 1.1654x; 1.1654x over previous
//
#include <hip/hip_runtime.h>

// PolicyNetGCN on MI355X — round 8.
// Edge build = block-aggregated 2-pass counting sort (NO per-edge global
// atomics — the ~52us invariant across rounds 4-7 was ~15G atomic/s):
//   phase1: per-block LDS histogram over 196 coarse buckets (256 rows) ->
//           LDS prefix sum -> ONE global atomicAdd per (block,bucket) to
//           reserve a run -> LDS-staged placement -> coalesced run copy.
//   phase2: one block per bucket; scatter ~4K entries into a zeroed 64 KB
//           LDS image (256 rows x 64 slots, LDS atomics), contiguous store.
// MFMA gemms; spmm = 2 channel-half passes, maskless, 8 gathers in flight.

typedef _Float16 fp16_t;
typedef _Float16 h2 __attribute__((ext_vector_type(2)));  // 4 B
typedef _Float16 h8 __attribute__((ext_vector_type(8)));  // 16 B
typedef float    f4 __attribute__((ext_vector_type(4)));
typedef unsigned long long ull;

#define CAP   64    // slots per row; P(deg>64 | ~Poisson(16)) ~ 2e-18
#define RPB   256   // rows per coarse bucket
#define BCAP  4608  // per-bucket capacity (mean 4096, sd 64 -> +8 sigma)
#define CHK   3200  // edges per phase-1 block (LDS staging capacity)

// phase 1: histogram -> scan -> reserve -> stage -> coalesced run copy
__global__ __launch_bounds__(256) void build1_k(const int* __restrict__ erow,
                                                const int* __restrict__ ecol,
                                                const float* __restrict__ ew,
                                                int* __restrict__ gcnt,
                                                ull* __restrict__ bed,
                                                int E, int NB) {
    __shared__ int hist[256], offs[256], cur[256], gbase[256];
    __shared__ ull stage[CHK];
    __shared__ unsigned short sbkt[CHK];
    int tid = threadIdx.x;
    int e0 = blockIdx.x * CHK;
    int e1 = e0 + CHK < E ? e0 + CHK : E;

    hist[tid] = 0;
    cur[tid] = 0;
    __syncthreads();
    for (int e = e0 + tid; e < e1; e += 256)
        atomicAdd(&hist[erow[e] >> 8], 1);
    __syncthreads();
    // inclusive Hillis-Steele scan -> exclusive offsets
    int v = hist[tid];
    offs[tid] = v;
    __syncthreads();
    for (int off = 1; off < 256; off <<= 1) {
        int t = (tid >= off) ? offs[tid - off] : 0;
        __syncthreads();
        offs[tid] += t;
        __syncthreads();
    }
    offs[tid] -= v;  // exclusive
    if (tid < NB && v > 0) gbase[tid] = atomicAdd(&gcnt[tid], v);
    __syncthreads();
    // place into LDS staging by local rank
    for (int e = e0 + tid; e < e1; e += 256) {
        int r = erow[e];
        int bk = r >> 8;
        unsigned q = (unsigned)(ew[e] * 32767.f + 0.5f);  // 15-bit fixed
        ull pv = ((ull)(r & 255) << 32) | (q << 17) | (unsigned)ecol[e];
        int idx = offs[bk] + atomicAdd(&cur[bk], 1);
        stage[idx] = pv;
        sbkt[idx] = (unsigned short)bk;
    }
    __syncthreads();
    // coalesced copy of per-bucket runs to reserved global ranges
    int total = e1 - e0;
    for (int i = tid; i < total; i += 256) {
        int bk = sbkt[i];
        int sl = gbase[bk] + (i - offs[bk]);
        if (sl < BCAP) bed[(size_t)bk * BCAP + sl] = stage[i];
    }
}

// phase 2: LDS-staged fine scatter, fully coalesced global writes
__global__ __launch_bounds__(256) void build2_k(const ull* __restrict__ bed,
                                                const int* __restrict__ gcnt,
                                                unsigned* __restrict__ ed,
                                                int* __restrict__ cnt, int N) {
    __shared__ unsigned sbuf[RPB * CAP];  // 64 KB
    __shared__ int scnt[RPB];
    int b = blockIdx.x, tid = threadIdx.x;
    for (int i = tid; i < RPB * CAP; i += 256) sbuf[i] = 0;
    scnt[tid] = 0;
    __syncthreads();
    int n = gcnt[b];
    n = n < BCAP ? n : BCAP;
    const ull* p = bed + (size_t)b * BCAP;
    for (int i = tid; i < n; i += 256) {
        ull v = p[i];
        int rl = (int)(v >> 32);
        int pos = atomicAdd(&scnt[rl], 1);
        if (pos < CAP) sbuf[(rl << 6) + pos] = (unsigned)v;
    }
    __syncthreads();
    size_t base = (size_t)b * (RPB * CAP);
    for (int i = tid; i < RPB * CAP; i += 256)
        ed[base + i] = sbuf[i];
    int r = b * RPB + tid;
    if (r < N) cnt[r] = scnt[tid] < CAP ? scnt[tid] : CAP;
}

// MFMA gemm: support[n, wave*64+p] = bias[p] + sum_k x[n,wave,k] * W[k,p]
// mfma_f32_16x16x32_f16 fragment maps (measured, m89/m91):
//   A: row=lane&15, k=8*(lane>>4)+t   B: col=lane&15, same k
//   C/D: col=lane&15, row=4*(lane>>4)+reg
template <int L1>
__global__ __launch_bounds__(256) void gemmM_k(const float* __restrict__ xf,
                                               const fp16_t* __restrict__ xh,
                                               const float* __restrict__ W,
                                               const float* __restrict__ bias,
                                               fp16_t* __restrict__ out, int N) {
    int wave = threadIdx.x >> 6;       // batch 0..3
    int lane = threadIdx.x & 63;
    int r16 = lane & 15, half = lane >> 4;

    h8 Bf[2][4];
#pragma unroll
    for (int kk = 0; kk < 2; ++kk)
#pragma unroll
        for (int j = 0; j < 4; ++j) {
            h8 v;
#pragma unroll
            for (int t = 0; t < 8; ++t)
                v[t] = (_Float16)W[(32 * kk + 8 * half + t) * 64 + 16 * j + r16];
            Bf[kk][j] = v;
        }
    float bj[4];
#pragma unroll
    for (int j = 0; j < 4; ++j) bj[j] = bias[16 * j + r16];

    int ntile = N >> 4;  // N % 16 == 0
    for (int tile = blockIdx.x; tile < ntile; tile += gridDim.x) {
        int row = tile * 16 + r16;
        h8 A0, A1;
        if (L1) {
            const float* p = xf + ((size_t)wave * N + row) * 64 + 8 * half;
            f4 u0 = *(const f4*)p;
            f4 u1 = *(const f4*)(p + 4);
            f4 u2 = *(const f4*)(p + 32);
            f4 u3 = *(const f4*)(p + 36);
#pragma unroll
            for (int t = 0; t < 4; ++t) {
                A0[t] = (_Float16)u0[t]; A0[t + 4] = (_Float16)u1[t];
                A1[t] = (_Float16)u2[t]; A1[t + 4] = (_Float16)u3[t];
            }
        } else {
            const fp16_t* p = xh + (size_t)row * 256 + wave * 64 + 8 * half;
            A0 = *(const h8*)p;
            A1 = *(const h8*)(p + 32);
        }
#pragma unroll
        for (int j = 0; j < 4; ++j) {
            f4 c = {0.f, 0.f, 0.f, 0.f};
            c = __builtin_amdgcn_mfma_f32_16x16x32_f16(A0, Bf[0][j], c, 0, 0, 0);
            c = __builtin_amdgcn_mfma_f32_16x16x32_f16(A1, Bf[1][j], c, 0, 0, 0);
#pragma unroll
            for (int r = 0; r < 4; ++r) {
                int orow = tile * 16 + 4 * half + r;
                out[(size_t)orow * 256 + wave * 64 + 16 * j + r16] =
                    (fp16_t)(c[r] + bj[j]);
            }
        }
    }
}

// One edge: decode packed (col|w15), gather 4 B (h2) of this pass's 256 B
// half-row, accumulate. Zero slots: w=0, col=0 (harmless read).
#define EDGE(pk)                                                               \
    {                                                                          \
        unsigned _p = (pk);                                                    \
        float _w = (float)(_p >> 17) * (1.f / 32767.f);                        \
        h2 _v = base[(size_t)(_p & 0x1FFFFu) * 128];                           \
        a0 += _w * (float)_v.x; a1 += _w * (float)_v.y;                        \
    }

// Wave = one output row; lane owns channel pair {2*(OFF+lane), +1}.
// 8 edges/iteration, maskless (slots zero-padded), 8 gathers in flight.
#define SPMM_CORE(OFF)                                                         \
    int rowi = blockIdx.x * 4 + (int)(threadIdx.x >> 6);                       \
    int lane = threadIdx.x & 63;                                               \
    int m = __builtin_amdgcn_readfirstlane(cnt[rowi]);                         \
    int mr = (m + 7) & ~7;                                                     \
    const unsigned* ep = ed + (size_t)rowi * CAP;                              \
    const h2* base = (const h2*)flat + (OFF) + lane;                           \
    float a0 = 0.f, a1 = 0.f;                                                  \
    for (int j = 0; j < mr; j += 8) {                                          \
        uint4 pA = *(const uint4*)(ep + j);                                    \
        uint4 pB = *(const uint4*)(ep + j + 4);                                \
        EDGE(pA.x) EDGE(pA.y) EDGE(pA.z) EDGE(pA.w)                            \
        EDGE(pB.x) EDGE(pB.y) EDGE(pB.z) EDGE(pB.w)                            \
    }

// layer-1 spmm pass: relu -> fp16 agg half
template <int PASS>
__global__ __launch_bounds__(256) void spmm1_k(const fp16_t* __restrict__ flat,
                                               const int* __restrict__ cnt,
                                               const unsigned* __restrict__ ed,
                                               fp16_t* __restrict__ agg, int N) {
    SPMM_CORE(PASS * 64)
    h2 r;
    r.x = (fp16_t)fmaxf(a0, 0.f);
    r.y = (fp16_t)fmaxf(a1, 0.f);
    ((h2*)agg)[(size_t)rowi * 128 + PASS * 64 + lane] = r;
}

// layer-2 spmm pass fused with head: pass owns batches {2*PASS, 2*PASS+1}.
// lane -> ch = 2*(PASS*64+lane); b = ch>>6; d = 2*(lane&31).
template <int PASS>
__global__ __launch_bounds__(256) void spmm2h_k(const fp16_t* __restrict__ flat,
                                                const int* __restrict__ cnt,
                                                const unsigned* __restrict__ ed,
                                                const float* __restrict__ wout,
                                                float* __restrict__ out, int N) {
    SPMM_CORE(PASS * 64)
    int b = 2 * PASS + (lane >> 5);
    float2 wo = ((const float2*)wout)[lane & 31];
    float p = fmaxf(a0, 0.f) * wo.x + fmaxf(a1, 0.f) * wo.y;
    p += __shfl_xor(p, 1); p += __shfl_xor(p, 2); p += __shfl_xor(p, 4);
    p += __shfl_xor(p, 8); p += __shfl_xor(p, 16);
    if ((lane & 31) == 0) out[(size_t)b * N + rowi] = p;
}

extern "C" void kernel_launch(void* const* d_in, const int* in_sizes, int n_in,
                              void* d_out, int out_size, void* d_ws, size_t ws_size,
                              hipStream_t stream) {
    const float* state = (const float*)d_in[0];
    const int*   erow  = (const int*)d_in[1];
    const int*   ecol  = (const int*)d_in[2];
    const float* ew    = (const float*)d_in[3];
    const float* W1    = (const float*)d_in[4];
    const float* b1    = (const float*)d_in[5];
    const float* W2    = (const float*)d_in[6];
    const float* b2    = (const float*)d_in[7];
    const float* wout  = (const float*)d_in[8];
    float* out = (float*)d_out;

    int N = in_sizes[0] / (4 * 64);  // 50000
    int E = in_sizes[1];             // 800000
    int NB = (N + RPB - 1) / RPB;    // 196 coarse buckets

    char* ws = (char*)d_ws;
    size_t off = 0;
    auto alloc = [&](size_t bytes) -> char* {
        char* p = ws + off;
        off += (bytes + 255) & ~(size_t)255;
        return p;
    };
    fp16_t*   flat = (fp16_t*)alloc((size_t)N * 256 * 2);            // 25.6 MB
    fp16_t*   agg  = (fp16_t*)alloc((size_t)N * 256 * 2);            // 25.6 MB
    int*      cnt  = (int*)alloc((size_t)NB * RPB * 4);              // 200 KB
    unsigned* ed   = (unsigned*)alloc((size_t)NB * RPB * CAP * 4);   // 12.85 MB
    int*      gcnt = (int*)alloc((size_t)NB * 4);                    // 784 B
    ull*      bed  = (ull*)alloc((size_t)NB * BCAP * 8);             // 7.2 MB
    if (off > ws_size) return;

    // --- two-phase edge build ---
    hipMemsetAsync(gcnt, 0, (size_t)NB * 4, stream);
    int nblk1 = (E + CHK - 1) / CHK;  // 250
    build1_k<<<nblk1, 256, 0, stream>>>(erow, ecol, ew, gcnt, bed, E, NB);
    build2_k<<<NB, 256, 0, stream>>>(bed, gcnt, ed, cnt, N);

    int sg = (N + 3) / 4;  // 12500 blocks, 4 rows each
    // --- layer 1 ---
    gemmM_k<1><<<1024, 256, 0, stream>>>(state, (const fp16_t*)nullptr, W1, b1, flat, N);
    spmm1_k<0><<<sg, 256, 0, stream>>>(flat, cnt, ed, agg, N);
    spmm1_k<1><<<sg, 256, 0, stream>>>(flat, cnt, ed, agg, N);
    // --- layer 2 + head ---
    gemmM_k<0><<<1024, 256, 0, stream>>>(nullptr, agg, W2, b2, flat, N);
    spmm2h_k<0><<<sg, 256, 0, stream>>>(flat, cnt, ed, wout, out, N);
    spmm2h_k<1><<<sg, 256, 0, stream>>>(flat, cnt, ed, wout, out, N);
}

// Round 9
// 169.846 us; speedup vs baseline: 1.2151x; 1.0426x over previous
//
#include <hip/hip_runtime.h>

// PolicyNetGCN on MI355X — round 9.
// build = block-aggregated 2-pass counting sort (round 8, unchanged).
// gemm1 = MFMA (fp32 state -> fp16 flat1).
// spmmG = spmm1 + gemm2 FUSED: block of 16 rows / 4 waves; each wave
//   gathers 4 full 512 B rows (maskless, 8 edges in flight), stages relu'd
//   agg in LDS, then computes its batch's 16x64 support2 tile with 8 MFMAs
//   (W2 frags in VGPRs) and writes flat2. No agg HBM round-trip.
// spmm2h = single-pass gather + fused actor head.

typedef _Float16 fp16_t;
typedef _Float16 h4 __attribute__((ext_vector_type(4)));  // 8 B
typedef _Float16 h8 __attribute__((ext_vector_type(8)));  // 16 B
typedef float    f4 __attribute__((ext_vector_type(4)));
typedef unsigned long long ull;

#define CAP   64    // slots per row; P(deg>64 | ~Poisson(16)) ~ 2e-18
#define RPB   256   // rows per coarse bucket
#define BCAP  4608  // per-bucket capacity (mean 4096, sd 64 -> +8 sigma)
#define CHK   3200  // edges per phase-1 block (LDS staging capacity)
#define LROW  264   // LDS agg row stride in fp16 (256 + 8 pad -> bank spread)

// build phase 1: histogram -> scan -> reserve(1 atomic/bucket) -> stage -> copy
__global__ __launch_bounds__(256) void build1_k(const int* __restrict__ erow,
                                                const int* __restrict__ ecol,
                                                const float* __restrict__ ew,
                                                int* __restrict__ gcnt,
                                                ull* __restrict__ bed,
                                                int E, int NB) {
    __shared__ int hist[256], offs[256], cur[256], gbase[256];
    __shared__ ull stage[CHK];
    __shared__ unsigned short sbkt[CHK];
    int tid = threadIdx.x;
    int e0 = blockIdx.x * CHK;
    int e1 = e0 + CHK < E ? e0 + CHK : E;

    hist[tid] = 0;
    cur[tid] = 0;
    __syncthreads();
    for (int e = e0 + tid; e < e1; e += 256)
        atomicAdd(&hist[erow[e] >> 8], 1);
    __syncthreads();
    int v = hist[tid];
    offs[tid] = v;
    __syncthreads();
    for (int off = 1; off < 256; off <<= 1) {
        int t = (tid >= off) ? offs[tid - off] : 0;
        __syncthreads();
        offs[tid] += t;
        __syncthreads();
    }
    offs[tid] -= v;  // exclusive
    if (tid < NB && v > 0) gbase[tid] = atomicAdd(&gcnt[tid], v);
    __syncthreads();
    for (int e = e0 + tid; e < e1; e += 256) {
        int r = erow[e];
        int bk = r >> 8;
        unsigned q = (unsigned)(ew[e] * 32767.f + 0.5f);  // 15-bit fixed
        ull pv = ((ull)(r & 255) << 32) | (q << 17) | (unsigned)ecol[e];
        int idx = offs[bk] + atomicAdd(&cur[bk], 1);
        stage[idx] = pv;
        sbkt[idx] = (unsigned short)bk;
    }
    __syncthreads();
    int total = e1 - e0;
    for (int i = tid; i < total; i += 256) {
        int bk = sbkt[i];
        int sl = gbase[bk] + (i - offs[bk]);
        if (sl < BCAP) bed[(size_t)bk * BCAP + sl] = stage[i];
    }
}

// build phase 2: LDS-staged fine scatter, fully coalesced global writes
__global__ __launch_bounds__(256) void build2_k(const ull* __restrict__ bed,
                                                const int* __restrict__ gcnt,
                                                unsigned* __restrict__ ed,
                                                int* __restrict__ cnt, int N) {
    __shared__ unsigned sbuf[RPB * CAP];  // 64 KB
    __shared__ int scnt[RPB];
    int b = blockIdx.x, tid = threadIdx.x;
    for (int i = tid; i < RPB * CAP; i += 256) sbuf[i] = 0;
    scnt[tid] = 0;
    __syncthreads();
    int n = gcnt[b];
    n = n < BCAP ? n : BCAP;
    const ull* p = bed + (size_t)b * BCAP;
    for (int i = tid; i < n; i += 256) {
        ull v = p[i];
        int rl = (int)(v >> 32);
        int pos = atomicAdd(&scnt[rl], 1);
        if (pos < CAP) sbuf[(rl << 6) + pos] = (unsigned)v;
    }
    __syncthreads();
    size_t base = (size_t)b * (RPB * CAP);
    for (int i = tid; i < RPB * CAP; i += 256)
        ed[base + i] = sbuf[i];
    int r = b * RPB + tid;
    if (r < N) cnt[r] = scnt[tid] < CAP ? scnt[tid] : CAP;
}

// MFMA gemm1: flat1[n, wave*64+p] = b1[p] + sum_k state[wave,n,k] * W1[k,p]
// mfma_f32_16x16x32_f16 fragment maps (measured, m89/m91):
//   A: row=lane&15, k=8*(lane>>4)+t   B: col=lane&15, same k
//   C/D: col=lane&15, row=4*(lane>>4)+reg
__global__ __launch_bounds__(256) void gemm1_k(const float* __restrict__ xf,
                                               const float* __restrict__ W,
                                               const float* __restrict__ bias,
                                               fp16_t* __restrict__ out, int N) {
    int wave = threadIdx.x >> 6;       // batch 0..3
    int lane = threadIdx.x & 63;
    int r16 = lane & 15, half = lane >> 4;

    h8 Bf[2][4];
#pragma unroll
    for (int kk = 0; kk < 2; ++kk)
#pragma unroll
        for (int j = 0; j < 4; ++j) {
            h8 v;
#pragma unroll
            for (int t = 0; t < 8; ++t)
                v[t] = (_Float16)W[(32 * kk + 8 * half + t) * 64 + 16 * j + r16];
            Bf[kk][j] = v;
        }
    float bj[4];
#pragma unroll
    for (int j = 0; j < 4; ++j) bj[j] = bias[16 * j + r16];

    int ntile = N >> 4;
    for (int tile = blockIdx.x; tile < ntile; tile += gridDim.x) {
        int row = tile * 16 + r16;
        const float* p = xf + ((size_t)wave * N + row) * 64 + 8 * half;
        f4 u0 = *(const f4*)p;
        f4 u1 = *(const f4*)(p + 4);
        f4 u2 = *(const f4*)(p + 32);
        f4 u3 = *(const f4*)(p + 36);
        h8 A0, A1;
#pragma unroll
        for (int t = 0; t < 4; ++t) {
            A0[t] = (_Float16)u0[t]; A0[t + 4] = (_Float16)u1[t];
            A1[t] = (_Float16)u2[t]; A1[t + 4] = (_Float16)u3[t];
        }
#pragma unroll
        for (int j = 0; j < 4; ++j) {
            f4 c = {0.f, 0.f, 0.f, 0.f};
            c = __builtin_amdgcn_mfma_f32_16x16x32_f16(A0, Bf[0][j], c, 0, 0, 0);
            c = __builtin_amdgcn_mfma_f32_16x16x32_f16(A1, Bf[1][j], c, 0, 0, 0);
#pragma unroll
            for (int r = 0; r < 4; ++r) {
                int orow = tile * 16 + 4 * half + r;
                out[(size_t)orow * 256 + wave * 64 + 16 * j + r16] =
                    (fp16_t)(c[r] + bj[j]);
            }
        }
    }
}

// One edge: decode (col17|w15), gather 8 B (h4) of the 512 B row, accumulate.
// Zero slots decode to col=0, w=0 (harmless read of row 0).
#define EDGE4(pk)                                                              \
    {                                                                          \
        unsigned _p = (pk);                                                    \
        float _w = (float)(_p >> 17) * (1.f / 32767.f);                        \
        h4 _v = base[(size_t)(_p & 0x1FFFFu) * 64];                            \
        a0 += _w * (float)_v.x; a1 += _w * (float)_v.y;                        \
        a2 += _w * (float)_v.z; a3 += _w * (float)_v.w;                        \
    }

// Gather one row (full 256 ch, lane owns 4): maskless, 8 gathers in flight.
#define GATHER_ROW(rowi)                                                       \
    a0 = a1 = a2 = a3 = 0.f;                                                   \
    {                                                                          \
        int m = __builtin_amdgcn_readfirstlane(cnt[rowi]);                     \
        int mr = (m + 7) & ~7;                                                 \
        const unsigned* ep = ed + (size_t)(rowi) * CAP;                        \
        for (int j = 0; j < mr; j += 8) {                                      \
            uint4 pA = *(const uint4*)(ep + j);                                \
            uint4 pB = *(const uint4*)(ep + j + 4);                            \
            EDGE4(pA.x) EDGE4(pA.y) EDGE4(pA.z) EDGE4(pA.w)                    \
            EDGE4(pB.x) EDGE4(pB.y) EDGE4(pB.z) EDGE4(pB.w)                    \
        }                                                                      \
    }

// spmm1 + gemm2 fused. Block = 16 rows, 4 waves; wave w gathers local rows
// 4w..4w+3 into LDS (relu'd fp16), then computes batch-w's 16x64 support2
// tile with 8 MFMAs (W2 frags in VGPRs) and writes flat2.
__global__ __launch_bounds__(256) void spmmG_k(const fp16_t* __restrict__ flat,
                                               const int* __restrict__ cnt,
                                               const unsigned* __restrict__ ed,
                                               const float* __restrict__ W,
                                               const float* __restrict__ bias,
                                               fp16_t* __restrict__ flat2, int N) {
    __shared__ fp16_t sagg[16 * LROW];  // 8.4 KB, +8 pad vs bank aliasing
    int wave = threadIdx.x >> 6;   // local row group / batch index
    int lane = threadIdx.x & 63;
    int r16 = lane & 15, half = lane >> 4;

    // W2 fragments + bias (same layout as gemm1)
    h8 Bf[2][4];
#pragma unroll
    for (int kk = 0; kk < 2; ++kk)
#pragma unroll
        for (int j = 0; j < 4; ++j) {
            h8 v;
#pragma unroll
            for (int t = 0; t < 8; ++t)
                v[t] = (_Float16)W[(32 * kk + 8 * half + t) * 64 + 16 * j + r16];
            Bf[kk][j] = v;
        }
    float bj[4];
#pragma unroll
    for (int j = 0; j < 4; ++j) bj[j] = bias[16 * j + r16];

    int blk0 = blockIdx.x * 16;
    const h4* base = (const h4*)flat + lane;
    float a0, a1, a2, a3;
#pragma unroll
    for (int rr = 0; rr < 4; ++rr) {
        int lr = wave * 4 + rr;
        GATHER_ROW(blk0 + lr)
        h4 r;
        r.x = (fp16_t)fmaxf(a0, 0.f);
        r.y = (fp16_t)fmaxf(a1, 0.f);
        r.z = (fp16_t)fmaxf(a2, 0.f);
        r.w = (fp16_t)fmaxf(a3, 0.f);
        *(h4*)&sagg[lr * LROW + lane * 4] = r;
    }
    __syncthreads();

    // gemm2: wave = batch. A: row=lane&15 (local row), k=8*half+t from LDS.
    h8 A0 = *(const h8*)&sagg[r16 * LROW + wave * 64 + 8 * half];
    h8 A1 = *(const h8*)&sagg[r16 * LROW + wave * 64 + 32 + 8 * half];
#pragma unroll
    for (int j = 0; j < 4; ++j) {
        f4 c = {0.f, 0.f, 0.f, 0.f};
        c = __builtin_amdgcn_mfma_f32_16x16x32_f16(A0, Bf[0][j], c, 0, 0, 0);
        c = __builtin_amdgcn_mfma_f32_16x16x32_f16(A1, Bf[1][j], c, 0, 0, 0);
#pragma unroll
        for (int r = 0; r < 4; ++r) {
            int orow = blk0 + 4 * half + r;
            flat2[(size_t)orow * 256 + wave * 64 + 16 * j + r16] =
                (fp16_t)(c[r] + bj[j]);
        }
    }
}

// spmm2 + actor head: out[b, rowi] = sum_d relu(agg2[b,d]) * wout[d].
// Lane owns ch 4*lane..4*lane+3 -> b = lane>>4, d = 4*(lane&15)+i.
__global__ __launch_bounds__(256) void spmm2h_k(const fp16_t* __restrict__ flat,
                                                const int* __restrict__ cnt,
                                                const unsigned* __restrict__ ed,
                                                const float* __restrict__ wout,
                                                float* __restrict__ out, int N) {
    int rowi = blockIdx.x * 4 + (int)(threadIdx.x >> 6);
    int lane = threadIdx.x & 63;
    const h4* base = (const h4*)flat + lane;
    float a0, a1, a2, a3;
    GATHER_ROW(rowi)
    int t = lane & 15, b = lane >> 4;
    float4 wo = ((const float4*)wout)[t];
    float p = fmaxf(a0, 0.f) * wo.x + fmaxf(a1, 0.f) * wo.y +
              fmaxf(a2, 0.f) * wo.z + fmaxf(a3, 0.f) * wo.w;
    p += __shfl_xor(p, 1); p += __shfl_xor(p, 2);
    p += __shfl_xor(p, 4); p += __shfl_xor(p, 8);
    if (t == 0) out[(size_t)b * N + rowi] = p;
}

extern "C" void kernel_launch(void* const* d_in, const int* in_sizes, int n_in,
                              void* d_out, int out_size, void* d_ws, size_t ws_size,
                              hipStream_t stream) {
    const float* state = (const float*)d_in[0];
    const int*   erow  = (const int*)d_in[1];
    const int*   ecol  = (const int*)d_in[2];
    const float* ew    = (const float*)d_in[3];
    const float* W1    = (const float*)d_in[4];
    const float* b1    = (const float*)d_in[5];
    const float* W2    = (const float*)d_in[6];
    const float* b2    = (const float*)d_in[7];
    const float* wout  = (const float*)d_in[8];
    float* out = (float*)d_out;

    int N = in_sizes[0] / (4 * 64);  // 50000
    int E = in_sizes[1];             // 800000
    int NB = (N + RPB - 1) / RPB;    // 196 coarse buckets

    char* ws = (char*)d_ws;
    size_t off = 0;
    auto alloc = [&](size_t bytes) -> char* {
        char* p = ws + off;
        off += (bytes + 255) & ~(size_t)255;
        return p;
    };
    fp16_t*   flat1 = (fp16_t*)alloc((size_t)N * 256 * 2);           // 25.6 MB
    fp16_t*   flat2 = (fp16_t*)alloc((size_t)N * 256 * 2);           // 25.6 MB
    int*      cnt   = (int*)alloc((size_t)NB * RPB * 4);             // 200 KB
    unsigned* ed    = (unsigned*)alloc((size_t)NB * RPB * CAP * 4);  // 12.85 MB
    int*      gcnt  = (int*)alloc((size_t)NB * 4);                   // 784 B
    ull*      bed   = (ull*)alloc((size_t)NB * BCAP * 8);            // 7.2 MB
    if (off > ws_size) return;

    // --- edge build ---
    hipMemsetAsync(gcnt, 0, (size_t)NB * 4, stream);
    int nblk1 = (E + CHK - 1) / CHK;  // 250
    build1_k<<<nblk1, 256, 0, stream>>>(erow, ecol, ew, gcnt, bed, E, NB);
    build2_k<<<NB, 256, 0, stream>>>(bed, gcnt, ed, cnt, N);

    // --- layer 1 gemm ---
    gemm1_k<<<1024, 256, 0, stream>>>(state, W1, b1, flat1, N);
    // --- layer 1 spmm + layer 2 gemm (fused) ---
    spmmG_k<<<N / 16, 256, 0, stream>>>(flat1, cnt, ed, W2, b2, flat2, N);
    // --- layer 2 spmm + head (fused) ---
    spmm2h_k<<<(N + 3) / 4, 256, 0, stream>>>(flat2, cnt, ed, wout, out, N);
}

// Round 10
// 166.804 us; speedup vs baseline: 1.2372x; 1.0182x over previous
//
#include <hip/hip_runtime.h>

// PolicyNetGCN on MI355X — round 10.
// build = block-aggregated 2-pass counting sort (round 8, unchanged).
// prepW  = pack W2/b2 into fragment order once (kills spmmG's per-block
//          scattered weight reads).
// gemm1  = MFMA (fp32 state -> fp16 flat1), grid-stride.
// spmmG  = spmm1+gemm2 fused; gathers PAIR-INTERLEAVED (2 rows per loop,
//          8 gathers continuously in flight, 2 drains/wave instead of 4),
//          coalesced fragment loads, LDS-staged agg, 8 MFMAs, write flat2.
// spmm2h = single-pass gather + fused actor head.

typedef _Float16 fp16_t;
typedef _Float16 h4 __attribute__((ext_vector_type(4)));  // 8 B
typedef _Float16 h8 __attribute__((ext_vector_type(8)));  // 16 B
typedef float    f4 __attribute__((ext_vector_type(4)));
typedef unsigned long long ull;

#define CAP   64    // slots per row; P(deg>64 | ~Poisson(16)) ~ 2e-18
#define RPB   256   // rows per coarse bucket
#define BCAP  4608  // per-bucket capacity (mean 4096, sd 64 -> +8 sigma)
#define CHK   3200  // edges per phase-1 block (LDS staging capacity)
#define LROW  264   // LDS agg row stride in fp16 (256 + 8 pad)

// build phase 1: histogram -> scan -> reserve(1 atomic/bucket) -> stage -> copy
__global__ __launch_bounds__(256) void build1_k(const int* __restrict__ erow,
                                                const int* __restrict__ ecol,
                                                const float* __restrict__ ew,
                                                int* __restrict__ gcnt,
                                                ull* __restrict__ bed,
                                                int E, int NB) {
    __shared__ int hist[256], offs[256], cur[256], gbase[256];
    __shared__ ull stage[CHK];
    __shared__ unsigned short sbkt[CHK];
    int tid = threadIdx.x;
    int e0 = blockIdx.x * CHK;
    int e1 = e0 + CHK < E ? e0 + CHK : E;

    hist[tid] = 0;
    cur[tid] = 0;
    __syncthreads();
    for (int e = e0 + tid; e < e1; e += 256)
        atomicAdd(&hist[erow[e] >> 8], 1);
    __syncthreads();
    int v = hist[tid];
    offs[tid] = v;
    __syncthreads();
    for (int off = 1; off < 256; off <<= 1) {
        int t = (tid >= off) ? offs[tid - off] : 0;
        __syncthreads();
        offs[tid] += t;
        __syncthreads();
    }
    offs[tid] -= v;  // exclusive
    if (tid < NB && v > 0) gbase[tid] = atomicAdd(&gcnt[tid], v);
    __syncthreads();
    for (int e = e0 + tid; e < e1; e += 256) {
        int r = erow[e];
        int bk = r >> 8;
        unsigned q = (unsigned)(ew[e] * 32767.f + 0.5f);  // 15-bit fixed
        ull pv = ((ull)(r & 255) << 32) | (q << 17) | (unsigned)ecol[e];
        int idx = offs[bk] + atomicAdd(&cur[bk], 1);
        stage[idx] = pv;
        sbkt[idx] = (unsigned short)bk;
    }
    __syncthreads();
    int total = e1 - e0;
    for (int i = tid; i < total; i += 256) {
        int bk = sbkt[i];
        int sl = gbase[bk] + (i - offs[bk]);
        if (sl < BCAP) bed[(size_t)bk * BCAP + sl] = stage[i];
    }
}

// build phase 2: LDS-staged fine scatter, fully coalesced global writes
__global__ __launch_bounds__(256) void build2_k(const ull* __restrict__ bed,
                                                const int* __restrict__ gcnt,
                                                unsigned* __restrict__ ed,
                                                int* __restrict__ cnt, int N) {
    __shared__ unsigned sbuf[RPB * CAP];  // 64 KB
    __shared__ int scnt[RPB];
    int b = blockIdx.x, tid = threadIdx.x;
    for (int i = tid; i < RPB * CAP; i += 256) sbuf[i] = 0;
    scnt[tid] = 0;
    __syncthreads();
    int n = gcnt[b];
    n = n < BCAP ? n : BCAP;
    const ull* p = bed + (size_t)b * BCAP;
    for (int i = tid; i < n; i += 256) {
        ull v = p[i];
        int rl = (int)(v >> 32);
        int pos = atomicAdd(&scnt[rl], 1);
        if (pos < CAP) sbuf[(rl << 6) + pos] = (unsigned)v;
    }
    __syncthreads();
    size_t base = (size_t)b * (RPB * CAP);
    for (int i = tid; i < RPB * CAP; i += 256)
        ed[base + i] = sbuf[i];
    int r = b * RPB + tid;
    if (r < N) cnt[r] = scnt[tid] < CAP ? scnt[tid] : CAP;
}

// pack W2/b2 into fragment order: wf[(kk*4+j)*64 + lane] (h8), bf[j*64+lane]
__global__ __launch_bounds__(64) void prepW_k(const float* __restrict__ W,
                                              const float* __restrict__ bias,
                                              fp16_t* __restrict__ wf,
                                              float* __restrict__ bf) {
    int lane = threadIdx.x;
    int r16 = lane & 15, half = lane >> 4;
#pragma unroll
    for (int kk = 0; kk < 2; ++kk)
#pragma unroll
        for (int j = 0; j < 4; ++j) {
            h8 v;
#pragma unroll
            for (int t = 0; t < 8; ++t)
                v[t] = (_Float16)W[(32 * kk + 8 * half + t) * 64 + 16 * j + r16];
            *(h8*)&wf[((kk * 4 + j) * 64 + lane) * 8] = v;
        }
#pragma unroll
    for (int j = 0; j < 4; ++j) bf[j * 64 + lane] = bias[16 * j + r16];
}

// MFMA gemm1: flat1[n, wave*64+p] = b1[p] + sum_k state[wave,n,k] * W1[k,p]
// mfma_f32_16x16x32_f16 fragment maps (measured, m89/m91):
//   A: row=lane&15, k=8*(lane>>4)+t   B: col=lane&15, same k
//   C/D: col=lane&15, row=4*(lane>>4)+reg
__global__ __launch_bounds__(256) void gemm1_k(const float* __restrict__ xf,
                                               const float* __restrict__ W,
                                               const float* __restrict__ bias,
                                               fp16_t* __restrict__ out, int N) {
    int wave = threadIdx.x >> 6;       // batch 0..3
    int lane = threadIdx.x & 63;
    int r16 = lane & 15, half = lane >> 4;

    h8 Bf[2][4];
#pragma unroll
    for (int kk = 0; kk < 2; ++kk)
#pragma unroll
        for (int j = 0; j < 4; ++j) {
            h8 v;
#pragma unroll
            for (int t = 0; t < 8; ++t)
                v[t] = (_Float16)W[(32 * kk + 8 * half + t) * 64 + 16 * j + r16];
            Bf[kk][j] = v;
        }
    float bj[4];
#pragma unroll
    for (int j = 0; j < 4; ++j) bj[j] = bias[16 * j + r16];

    int ntile = N >> 4;
    for (int tile = blockIdx.x; tile < ntile; tile += gridDim.x) {
        int row = tile * 16 + r16;
        const float* p = xf + ((size_t)wave * N + row) * 64 + 8 * half;
        f4 u0 = *(const f4*)p;
        f4 u1 = *(const f4*)(p + 4);
        f4 u2 = *(const f4*)(p + 32);
        f4 u3 = *(const f4*)(p + 36);
        h8 A0, A1;
#pragma unroll
        for (int t = 0; t < 4; ++t) {
            A0[t] = (_Float16)u0[t]; A0[t + 4] = (_Float16)u1[t];
            A1[t] = (_Float16)u2[t]; A1[t + 4] = (_Float16)u3[t];
        }
#pragma unroll
        for (int j = 0; j < 4; ++j) {
            f4 c = {0.f, 0.f, 0.f, 0.f};
            c = __builtin_amdgcn_mfma_f32_16x16x32_f16(A0, Bf[0][j], c, 0, 0, 0);
            c = __builtin_amdgcn_mfma_f32_16x16x32_f16(A1, Bf[1][j], c, 0, 0, 0);
#pragma unroll
            for (int r = 0; r < 4; ++r) {
                int orow = tile * 16 + 4 * half + r;
                out[(size_t)orow * 256 + wave * 64 + 16 * j + r16] =
                    (fp16_t)(c[r] + bj[j]);
            }
        }
    }
}

// One edge: decode (col17|w15), gather 8 B (h4) of the 512 B row into the
// named accumulators. Zero slots: col=0, w=0 (harmless L2-hot read).
#define EDGE4(pk, A0, A1, A2, A3)                                              \
    {                                                                          \
        unsigned _p = (pk);                                                    \
        float _w = (float)(_p >> 17) * (1.f / 32767.f);                        \
        h4 _v = base[(size_t)(_p & 0x1FFFFu) * 64];                            \
        A0 += _w * (float)_v.x; A1 += _w * (float)_v.y;                        \
        A2 += _w * (float)_v.z; A3 += _w * (float)_v.w;                        \
    }

// spmm1 + gemm2 fused. Block = 16 rows, 4 waves; wave w gathers local rows
// 4w..4w+3 PAIRWISE-interleaved into LDS (relu'd fp16), then computes
// batch-w's 16x64 support2 tile with 8 MFMAs and writes flat2.
__global__ __launch_bounds__(256) void spmmG_k(const fp16_t* __restrict__ flat,
                                               const int* __restrict__ cnt,
                                               const unsigned* __restrict__ ed,
                                               const fp16_t* __restrict__ wf,
                                               const float* __restrict__ bf,
                                               fp16_t* __restrict__ flat2, int N) {
    __shared__ fp16_t sagg[16 * LROW];  // 8.4 KB
    int wave = threadIdx.x >> 6;   // local row group / batch index
    int lane = threadIdx.x & 63;
    int r16 = lane & 15, half = lane >> 4;

    // fragment-ordered W2/b2: 8 coalesced 16 B loads + 4 scalar loads
    h8 Bf[8];
#pragma unroll
    for (int i = 0; i < 8; ++i) Bf[i] = ((const h8*)wf)[i * 64 + lane];
    float bj[4];
#pragma unroll
    for (int j = 0; j < 4; ++j) bj[j] = bf[j * 64 + lane];

    int blk0 = blockIdx.x * 16;
    const h4* base = (const h4*)flat + lane;

#pragma unroll
    for (int pr = 0; pr < 2; ++pr) {   // two row-pairs per wave
        int lr0 = wave * 4 + 2 * pr;
        int r0 = blk0 + lr0, r1 = r0 + 1;
        int m0 = __builtin_amdgcn_readfirstlane(cnt[r0]);
        int m1 = __builtin_amdgcn_readfirstlane(cnt[r1]);
        int mm = m0 > m1 ? m0 : m1;
        int mr = (mm + 3) & ~3;
        const unsigned* e0 = ed + (size_t)r0 * CAP;
        const unsigned* e1 = ed + (size_t)r1 * CAP;
        float a0 = 0.f, a1 = 0.f, a2 = 0.f, a3 = 0.f;
        float c0 = 0.f, c1 = 0.f, c2 = 0.f, c3 = 0.f;
        for (int j = 0; j < mr; j += 4) {  // 8 gathers in flight (4+4)
            uint4 pA = *(const uint4*)(e0 + j);
            uint4 pB = *(const uint4*)(e1 + j);
            EDGE4(pA.x, a0, a1, a2, a3) EDGE4(pB.x, c0, c1, c2, c3)
            EDGE4(pA.y, a0, a1, a2, a3) EDGE4(pB.y, c0, c1, c2, c3)
            EDGE4(pA.z, a0, a1, a2, a3) EDGE4(pB.z, c0, c1, c2, c3)
            EDGE4(pA.w, a0, a1, a2, a3) EDGE4(pB.w, c0, c1, c2, c3)
        }
        h4 s0, s1;
        s0.x = (fp16_t)fmaxf(a0, 0.f); s0.y = (fp16_t)fmaxf(a1, 0.f);
        s0.z = (fp16_t)fmaxf(a2, 0.f); s0.w = (fp16_t)fmaxf(a3, 0.f);
        s1.x = (fp16_t)fmaxf(c0, 0.f); s1.y = (fp16_t)fmaxf(c1, 0.f);
        s1.z = (fp16_t)fmaxf(c2, 0.f); s1.w = (fp16_t)fmaxf(c3, 0.f);
        *(h4*)&sagg[lr0 * LROW + lane * 4] = s0;
        *(h4*)&sagg[(lr0 + 1) * LROW + lane * 4] = s1;
    }
    __syncthreads();

    // gemm2: wave = batch. A: row=lane&15 (local), k=8*half+t from LDS.
    h8 A0 = *(const h8*)&sagg[r16 * LROW + wave * 64 + 8 * half];
    h8 A1 = *(const h8*)&sagg[r16 * LROW + wave * 64 + 32 + 8 * half];
#pragma unroll
    for (int j = 0; j < 4; ++j) {
        f4 c = {0.f, 0.f, 0.f, 0.f};
        c = __builtin_amdgcn_mfma_f32_16x16x32_f16(A0, Bf[j], c, 0, 0, 0);
        c = __builtin_amdgcn_mfma_f32_16x16x32_f16(A1, Bf[4 + j], c, 0, 0, 0);
#pragma unroll
        for (int r = 0; r < 4; ++r) {
            int orow = blk0 + 4 * half + r;
            flat2[(size_t)orow * 256 + wave * 64 + 16 * j + r16] =
                (fp16_t)(c[r] + bj[j]);
        }
    }
}

// spmm2 + actor head: out[b, rowi] = sum_d relu(agg2[b,d]) * wout[d].
// Lane owns ch 4*lane..4*lane+3 -> b = lane>>4, d = 4*(lane&15)+i.
__global__ __launch_bounds__(256) void spmm2h_k(const fp16_t* __restrict__ flat,
                                                const int* __restrict__ cnt,
                                                const unsigned* __restrict__ ed,
                                                const float* __restrict__ wout,
                                                float* __restrict__ out, int N) {
    int rowi = blockIdx.x * 4 + (int)(threadIdx.x >> 6);
    int lane = threadIdx.x & 63;
    const h4* base = (const h4*)flat + lane;
    int m = __builtin_amdgcn_readfirstlane(cnt[rowi]);
    int mr = (m + 7) & ~7;
    const unsigned* ep = ed + (size_t)rowi * CAP;
    float a0 = 0.f, a1 = 0.f, a2 = 0.f, a3 = 0.f;
    for (int j = 0; j < mr; j += 8) {
        uint4 pA = *(const uint4*)(ep + j);
        uint4 pB = *(const uint4*)(ep + j + 4);
        EDGE4(pA.x, a0, a1, a2, a3) EDGE4(pA.y, a0, a1, a2, a3)
        EDGE4(pA.z, a0, a1, a2, a3) EDGE4(pA.w, a0, a1, a2, a3)
        EDGE4(pB.x, a0, a1, a2, a3) EDGE4(pB.y, a0, a1, a2, a3)
        EDGE4(pB.z, a0, a1, a2, a3) EDGE4(pB.w, a0, a1, a2, a3)
    }
    int t = lane & 15, b = lane >> 4;
    float4 wo = ((const float4*)wout)[t];
    float p = fmaxf(a0, 0.f) * wo.x + fmaxf(a1, 0.f) * wo.y +
              fmaxf(a2, 0.f) * wo.z + fmaxf(a3, 0.f) * wo.w;
    p += __shfl_xor(p, 1); p += __shfl_xor(p, 2);
    p += __shfl_xor(p, 4); p += __shfl_xor(p, 8);
    if (t == 0) out[(size_t)b * N + rowi] = p;
}

extern "C" void kernel_launch(void* const* d_in, const int* in_sizes, int n_in,
                              void* d_out, int out_size, void* d_ws, size_t ws_size,
                              hipStream_t stream) {
    const float* state = (const float*)d_in[0];
    const int*   erow  = (const int*)d_in[1];
    const int*   ecol  = (const int*)d_in[2];
    const float* ew    = (const float*)d_in[3];
    const float* W1    = (const float*)d_in[4];
    const float* b1    = (const float*)d_in[5];
    const float* W2    = (const float*)d_in[6];
    const float* b2    = (const float*)d_in[7];
    const float* wout  = (const float*)d_in[8];
    float* out = (float*)d_out;

    int N = in_sizes[0] / (4 * 64);  // 50000
    int E = in_sizes[1];             // 800000
    int NB = (N + RPB - 1) / RPB;    // 196 coarse buckets

    char* ws = (char*)d_ws;
    size_t off = 0;
    auto alloc = [&](size_t bytes) -> char* {
        char* p = ws + off;
        off += (bytes + 255) & ~(size_t)255;
        return p;
    };
    fp16_t*   flat1 = (fp16_t*)alloc((size_t)N * 256 * 2);           // 25.6 MB
    fp16_t*   flat2 = (fp16_t*)alloc((size_t)N * 256 * 2);           // 25.6 MB
    int*      cnt   = (int*)alloc((size_t)NB * RPB * 4);             // 200 KB
    unsigned* ed    = (unsigned*)alloc((size_t)NB * RPB * CAP * 4);  // 12.85 MB
    int*      gcnt  = (int*)alloc((size_t)NB * 4);                   // 784 B
    ull*      bed   = (ull*)alloc((size_t)NB * BCAP * 8);            // 7.2 MB
    fp16_t*   wf    = (fp16_t*)alloc(8 * 64 * 8 * 2);                // 8 KB
    float*    bfr   = (float*)alloc(4 * 64 * 4);                     // 1 KB
    if (off > ws_size) return;

    // --- edge build ---
    hipMemsetAsync(gcnt, 0, (size_t)NB * 4, stream);
    int nblk1 = (E + CHK - 1) / CHK;  // 250
    build1_k<<<nblk1, 256, 0, stream>>>(erow, ecol, ew, gcnt, bed, E, NB);
    build2_k<<<NB, 256, 0, stream>>>(bed, gcnt, ed, cnt, N);
    prepW_k<<<1, 64, 0, stream>>>(W2, b2, wf, bfr);

    // --- layer 1 gemm ---
    gemm1_k<<<1024, 256, 0, stream>>>(state, W1, b1, flat1, N);
    // --- layer 1 spmm + layer 2 gemm (fused) ---
    spmmG_k<<<N / 16, 256, 0, stream>>>(flat1, cnt, ed, wf, bfr, flat2, N);
    // --- layer 2 spmm + head (fused) ---
    spmm2h_k<<<(N + 3) / 4, 256, 0, stream>>>(flat2, cnt, ed, wout, out, N);
}